// Round 3
// baseline (471.263 us; speedup 1.0000x reference)
//
#include <hip/hip_runtime.h>

// Problem config (fixed by the reference's setup_inputs)
constexpr int B     = 8;      // batch
constexpr int L     = 1024;   // new tokens per seq
constexpr int BS    = 16;     // block size (tokens per cache block)
constexpr int MAXB  = 128;    // max blocks per seq (layer slice of block_tables)
constexpr int H     = 8;      // kv heads
constexpr int D     = 128;    // head dim
constexpr int TOTAL = 2048;   // total physical blocks (= free_blocks size)
constexpr int CACHE_ELEMS = TOTAL * H * BS * D;   // 33,554,432 floats per cache

// Clang vector type: __builtin_nontemporal_* requires a true vector type,
// not HIP_vector_type<float,4>. Same 16B layout -> global_*_dwordx4 nt.
typedef float f4 __attribute__((ext_vector_type(4)));

// ---------------------------------------------------------------------------
// Kernel A: rebuild the block-allocation inverse map.
// inv[blk] = (b << 20) | slot   if physical block `blk` receives new tokens
//          = -1                 otherwise
// Mirrors the reference's cumsum tail-pop allocation exactly, computed from
// the live inputs (no hardcoded allocation results).
// ---------------------------------------------------------------------------
__global__ void build_inv_kernel(const int* __restrict__ input_len,
                                 const int* __restrict__ block_tables,
                                 const int* __restrict__ seq_lens,
                                 const int* __restrict__ free_blocks,
                                 int* __restrict__ inv) {
    const int tid = threadIdx.x;
    for (int i = tid; i < TOTAL; i += blockDim.x) inv[i] = -1;
    __syncthreads();

    // Every thread redundantly computes the tiny (B=8) allocation prefix sums.
    int old_nb[B], new_nb[B], start[B];
    int cum = 0;
    for (int b = 0; b < B; ++b) {
        const int sl = seq_lens[b];
        old_nb[b] = (sl + BS - 1) / BS;
        new_nb[b] = (sl + input_len[b] + BS - 1) / BS;
        cum += new_nb[b] - old_nb[b];
        start[b] = TOTAL - cum;              // num_free == TOTAL
    }

    // Slots that receive at least one new token: j in [seq_lens/BS, new_nb)
    for (int b = 0; b < B; ++b) {
        const int j0 = seq_lens[b] / BS;
        for (int j = j0 + tid; j < new_nb[b]; j += blockDim.x) {
            int blk;
            if (j >= old_nb[b]) {
                int fi = start[b] + (j - old_nb[b]);
                fi = min(max(fi, 0), TOTAL - 1);   // reference's clip
                blk = free_blocks[fi];
            } else {
                blk = block_tables[b * MAXB + j];  // existing partial block
            }
            inv[blk] = (b << 20) | j;
        }
    }
}

// ---------------------------------------------------------------------------
// Kernel B: one-pass gather producing the full [2, TOTAL, H, BS, D] output.
// Each 256-thread workgroup emits ONE FULL cache block (4096 float4 = 64 KiB);
// each thread handles CH=16 float4 (256 B), chunk-strided by 256 so every
// load/store instruction is a fully-coalesced 4 KiB slab.
// CH=16 (vs 8): halves WG-churn/store-drain bubbles at residency-batch
// boundaries and amortizes the per-WG prologue (inv + seq scalars) 2x.
// c / blk / inv[blk] / per-sequence scalars are workgroup-uniform.
// All traffic is stream-once -> non-temporal hints keep L2 clean.
// ---------------------------------------------------------------------------
__global__ __launch_bounds__(256) void gather_out_kernel(
        const f4* __restrict__ key_states,
        const f4* __restrict__ value_states,
        const f4* __restrict__ k_cache,
        const f4* __restrict__ v_cache,
        const int* __restrict__ input_len,
        const int* __restrict__ cu_seqlens,
        const int* __restrict__ seq_lens,
        const int* __restrict__ inv,
        f4*        __restrict__ out) {
    constexpr int C4   = CACHE_ELEMS / 4;   // float4 per cache: 8,388,608
    constexpr int PB4  = H * BS * D / 4;    // float4 per block: 4096
    constexpr int CH   = 16;                // float4 per thread
    constexpr int WG4  = 256 * CH;          // float4 per workgroup: 4096 = PB4

    // base index of this thread's first float4 in the [2, TOTAL, H, BS, D] out
    const int base = blockIdx.x * WG4 + threadIdx.x;

    // WG4 == PB4 -> each workgroup is exactly one (c, blk) cache block.
    const int c    = base >= C4 ? 1 : 0;    // 0 = K, 1 = V
    const int rel0 = base - c * C4;
    const int blk  = rel0 >> 12;            // / PB4
    const int tid  = threadIdx.x;

    const f4* __restrict__ cache = c ? v_cache : k_cache;
    const int m = inv[blk];

    f4 vals[CH];
    if (m >= 0) {
        const int b    = m >> 20;
        const int j    = m & 0xFFFFF;
        const int sl   = seq_lens[b];
        const int il   = input_len[b];
        const int tok0 = cu_seqlens[b] - sl;   // tok = tok0 + pos
        const f4* __restrict__ src = c ? value_states : key_states;
        #pragma unroll
        for (int k = 0; k < CH; ++k) {
            const int r    = tid + k * 256;     // offset within the block
            const int h    = r >> 9;            // / (BS*D/4)
            const int off  = (r >> 5) & 15;     // token within block
            const int d4   = r & 31;
            const int pos  = j * BS + off;
            if (pos >= sl && pos < sl + il) {
                vals[k] = __builtin_nontemporal_load(
                    &src[(tok0 + pos) * (H * D / 4) + h * 32 + d4]);
            } else {
                vals[k] = __builtin_nontemporal_load(&cache[rel0 + k * 256]);
            }
        }
    } else {
        #pragma unroll
        for (int k = 0; k < CH; ++k)
            vals[k] = __builtin_nontemporal_load(&cache[rel0 + k * 256]);
    }

    #pragma unroll
    for (int k = 0; k < CH; ++k)
        __builtin_nontemporal_store(vals[k], &out[base + k * 256]);
}

extern "C" void kernel_launch(void* const* d_in, const int* in_sizes, int n_in,
                              void* d_out, int out_size, void* d_ws, size_t ws_size,
                              hipStream_t stream) {
    // setup_inputs order:
    // 0 layer_idx, 1 key_states, 2 value_states, 3 input_len, 4 cu_seqlens,
    // 5 k_cache, 6 v_cache, 7 block_tables, 8 seq_lens, 9 free_blocks
    const float* key_states   = (const float*)d_in[1];
    const float* value_states = (const float*)d_in[2];
    const int*   input_len    = (const int*)d_in[3];
    const int*   cu_seqlens   = (const int*)d_in[4];
    const float* k_cache      = (const float*)d_in[5];
    const float* v_cache      = (const float*)d_in[6];
    const int*   block_tables = (const int*)d_in[7];
    const int*   seq_lens     = (const int*)d_in[8];
    const int*   free_blocks  = (const int*)d_in[9];

    int* inv = (int*)d_ws;                  // TOTAL ints = 8 KiB of workspace

    build_inv_kernel<<<1, 256, 0, stream>>>(input_len, block_tables, seq_lens,
                                            free_blocks, inv);

    constexpr int WG4    = 256 * 16;                // float4 per workgroup
    const int     total4 = 2 * CACHE_ELEMS / 4;     // 16,777,216 float4
    const int     blocks = total4 / WG4;            // 4096 (exact)
    gather_out_kernel<<<blocks, 256, 0, stream>>>(
        (const f4*)key_states, (const f4*)value_states,
        (const f4*)k_cache, (const f4*)v_cache,
        input_len, cu_seqlens, seq_lens, inv, (f4*)d_out);
}

// Round 4
// 463.162 us; speedup vs baseline: 1.0175x; 1.0175x over previous
//
#include <hip/hip_runtime.h>

// Problem config (fixed by the reference's setup_inputs)
constexpr int B     = 8;      // batch
constexpr int L     = 1024;   // new tokens per seq
constexpr int BS    = 16;     // block size (tokens per cache block)
constexpr int MAXB  = 128;    // max blocks per seq (layer slice of block_tables)
constexpr int H     = 8;      // kv heads
constexpr int D     = 128;    // head dim
constexpr int TOTAL = 2048;   // total physical blocks (= free_blocks size)
constexpr int CACHE_ELEMS = TOTAL * H * BS * D;   // 33,554,432 floats per cache

// Clang vector type: __builtin_nontemporal_* requires a true vector type,
// not HIP_vector_type<float,4>. Same 16B layout -> global_*_dwordx4 nt.
typedef float f4 __attribute__((ext_vector_type(4)));

// ---------------------------------------------------------------------------
// Kernel A: rebuild the block-allocation inverse map.
// inv[blk] = (b << 20) | slot   if physical block `blk` receives new tokens
//          = -1                 otherwise
// Mirrors the reference's cumsum tail-pop allocation exactly, computed from
// the live inputs (no hardcoded allocation results).
// ---------------------------------------------------------------------------
__global__ void build_inv_kernel(const int* __restrict__ input_len,
                                 const int* __restrict__ block_tables,
                                 const int* __restrict__ seq_lens,
                                 const int* __restrict__ free_blocks,
                                 int* __restrict__ inv) {
    const int tid = threadIdx.x;
    for (int i = tid; i < TOTAL; i += blockDim.x) inv[i] = -1;
    __syncthreads();

    // Every thread redundantly computes the tiny (B=8) allocation prefix sums.
    int old_nb[B], new_nb[B], start[B];
    int cum = 0;
    for (int b = 0; b < B; ++b) {
        const int sl = seq_lens[b];
        old_nb[b] = (sl + BS - 1) / BS;
        new_nb[b] = (sl + input_len[b] + BS - 1) / BS;
        cum += new_nb[b] - old_nb[b];
        start[b] = TOTAL - cum;              // num_free == TOTAL
    }

    // Slots that receive at least one new token: j in [seq_lens/BS, new_nb)
    for (int b = 0; b < B; ++b) {
        const int j0 = seq_lens[b] / BS;
        for (int j = j0 + tid; j < new_nb[b]; j += blockDim.x) {
            int blk;
            if (j >= old_nb[b]) {
                int fi = start[b] + (j - old_nb[b]);
                fi = min(max(fi, 0), TOTAL - 1);   // reference's clip
                blk = free_blocks[fi];
            } else {
                blk = block_tables[b * MAXB + j];  // existing partial block
            }
            inv[blk] = (b << 20) | j;
        }
    }
}

// ---------------------------------------------------------------------------
// Kernel B: one-pass gather producing the full [2, TOTAL, H, BS, D] output.
// Each 256-thread workgroup emits HALF of one cache block (2048 float4);
// each thread handles CH=8 float4 (128 B), chunk-strided by 256 so every
// load/store instruction is a fully-coalesced 4 KiB slab.
// CH=8 chosen over 16: vals[16] costs 64 VGPR alone and dropped occupancy
// to ~5 waves/SIMD (round-3 regression). __launch_bounds__(256, 8) pins
// VGPR <= 64 so 8 waves/SIMD (32/CU) hide the ~900-cycle HBM latency.
// c / blk / inv[blk] / per-sequence scalars are workgroup-uniform.
// All traffic is stream-once -> non-temporal hints keep L2 clean.
// ---------------------------------------------------------------------------
__global__ __launch_bounds__(256, 8) void gather_out_kernel(
        const f4* __restrict__ key_states,
        const f4* __restrict__ value_states,
        const f4* __restrict__ k_cache,
        const f4* __restrict__ v_cache,
        const int* __restrict__ input_len,
        const int* __restrict__ cu_seqlens,
        const int* __restrict__ seq_lens,
        const int* __restrict__ inv,
        f4*        __restrict__ out) {
    constexpr int C4   = CACHE_ELEMS / 4;   // float4 per cache: 8,388,608
    constexpr int PB4  = H * BS * D / 4;    // float4 per block: 4096
    constexpr int CH   = 8;                 // float4 per thread
    constexpr int WG4  = 256 * CH;          // float4 per workgroup: 2048

    // base index of this thread's first float4 in the [2, TOTAL, H, BS, D] out
    const int base = blockIdx.x * WG4 + threadIdx.x;

    // WG4 (2048) divides PB4 (4096) -> c and blk are uniform across the WG.
    const int c    = base >= C4 ? 1 : 0;    // 0 = K, 1 = V
    const int rel0 = base - c * C4;
    const int blk  = rel0 >> 12;            // / PB4

    const f4* __restrict__ cache = c ? v_cache : k_cache;
    const int m = inv[blk];

    f4 vals[CH];
    if (m >= 0) {
        const int b    = m >> 20;
        const int j    = m & 0xFFFFF;
        const int sl   = seq_lens[b];
        const int il   = input_len[b];
        const int tok0 = cu_seqlens[b] - sl;   // tok = tok0 + pos
        const f4* __restrict__ src = c ? value_states : key_states;
        #pragma unroll
        for (int k = 0; k < CH; ++k) {
            const int rel4 = rel0 + k * 256;
            const int r    = rel4 & (PB4 - 1);
            const int h    = r >> 9;            // / (BS*D/4)
            const int off  = (r >> 5) & 15;     // token within block
            const int d4   = r & 31;
            const int pos  = j * BS + off;
            if (pos >= sl && pos < sl + il) {
                vals[k] = __builtin_nontemporal_load(
                    &src[(tok0 + pos) * (H * D / 4) + h * 32 + d4]);
            } else {
                vals[k] = __builtin_nontemporal_load(&cache[rel4]);
            }
        }
    } else {
        #pragma unroll
        for (int k = 0; k < CH; ++k)
            vals[k] = __builtin_nontemporal_load(&cache[rel0 + k * 256]);
    }

    #pragma unroll
    for (int k = 0; k < CH; ++k)
        __builtin_nontemporal_store(vals[k], &out[base + k * 256]);
}

extern "C" void kernel_launch(void* const* d_in, const int* in_sizes, int n_in,
                              void* d_out, int out_size, void* d_ws, size_t ws_size,
                              hipStream_t stream) {
    // setup_inputs order:
    // 0 layer_idx, 1 key_states, 2 value_states, 3 input_len, 4 cu_seqlens,
    // 5 k_cache, 6 v_cache, 7 block_tables, 8 seq_lens, 9 free_blocks
    const float* key_states   = (const float*)d_in[1];
    const float* value_states = (const float*)d_in[2];
    const int*   input_len    = (const int*)d_in[3];
    const int*   cu_seqlens   = (const int*)d_in[4];
    const float* k_cache      = (const float*)d_in[5];
    const float* v_cache      = (const float*)d_in[6];
    const int*   block_tables = (const int*)d_in[7];
    const int*   seq_lens     = (const int*)d_in[8];
    const int*   free_blocks  = (const int*)d_in[9];

    int* inv = (int*)d_ws;                  // TOTAL ints = 8 KiB of workspace

    build_inv_kernel<<<1, 256, 0, stream>>>(input_len, block_tables, seq_lens,
                                            free_blocks, inv);

    constexpr int WG4    = 256 * 8;                 // float4 per workgroup
    const int     total4 = 2 * CACHE_ELEMS / 4;     // 16,777,216 float4
    const int     blocks = total4 / WG4;            // 8192 (exact)
    gather_out_kernel<<<blocks, 256, 0, stream>>>(
        (const f4*)key_states, (const f4*)value_states,
        (const f4*)k_cache, (const f4*)v_cache,
        input_len, cu_seqlens, seq_lens, inv, (f4*)d_out);
}